// Round 6
// baseline (825.842 us; speedup 1.0000x reference)
//
#include <hip/hip_runtime.h>

constexpr int NN  = 50000;   // nodes
constexpr int NE  = 800000;  // edges
constexpr int CIN = 128;     // input channels
constexpr int CH  = 256;     // hidden channels
constexpr int NG  = 512;     // graphs
constexpr int NSLICE  = 8;           // = XCD count
constexpr int SLICE_N = NN / NSLICE; // 6250 nodes per slice

typedef unsigned short ushort_t;
typedef unsigned int uint_t;

static __device__ __forceinline__ ushort_t f2bf(float f) {
    uint_t u = __float_as_uint(f);
    u += 0x7fffu + ((u >> 16) & 1u);   // round-to-nearest-even
    return (ushort_t)(u >> 16);
}

// ================= prep: fp32 -> bf16 converts =================
__global__ void conv_x_kernel(const float4* __restrict__ x, ushort4* __restrict__ xb, int n4) {
    int i = blockIdx.x * blockDim.x + threadIdx.x;
    if (i >= n4) return;
    float4 v = x[i];
    ushort4 o;
    o.x = f2bf(v.x); o.y = f2bf(v.y); o.z = f2bf(v.z); o.w = f2bf(v.w);
    xb[i] = o;
}

// Wt[n*K + k] = bf16(W[k*N + n])
__global__ void conv_wt_kernel(const float* __restrict__ W, ushort_t* __restrict__ Wt, int K, int N) {
    int i = blockIdx.x * blockDim.x + threadIdx.x;
    if (i >= K * N) return;
    int k = i / N, n = i % N;
    Wt[(size_t)n * K + k] = f2bf(W[i]);
}

// ================= counting =================
__global__ void count_kernel(const int* __restrict__ dst, int* __restrict__ cnt, int E) {
    int e = blockIdx.x * blockDim.x + threadIdx.x;
    if (e < E) atomicAdd(&cnt[dst[e]], 1);
}

// deg + (slice,dst)-bucket counts in one pass
__global__ void count_both_kernel(const int* __restrict__ src, const int* __restrict__ dst,
                                  int* __restrict__ deg, int* __restrict__ cnt2, int E) {
    int e = blockIdx.x * blockDim.x + threadIdx.x;
    if (e >= E) return;
    int d = dst[e], s = src[e];
    atomicAdd(&deg[d], 1);
    atomicAdd(&cnt2[(s / SLICE_N) * NN + d], 1);
}

__global__ void dinv_from_deg_kernel(const int* __restrict__ deg, float* __restrict__ dinv, int n) {
    int i = blockIdx.x * blockDim.x + threadIdx.x;
    if (i < n) dinv[i] = rsqrtf((float)deg[i] + 1.0f);   // +1 self loop
}

// ================= scan building blocks =================
__global__ __launch_bounds__(256) void scan_bsum_kernel(const int* __restrict__ cnt,
                                                        int* __restrict__ bsum, int n) {
    int i = blockIdx.x * 256 + threadIdx.x;
    int v = (i < n) ? cnt[i] : 0;
    #pragma unroll
    for (int off = 32; off >= 1; off >>= 1) v += __shfl_xor(v, off, 64);
    __shared__ int ws[4];
    if ((threadIdx.x & 63) == 0) ws[threadIdx.x >> 6] = v;
    __syncthreads();
    if (threadIdx.x == 0) bsum[blockIdx.x] = ws[0] + ws[1] + ws[2] + ws[3];
}

__global__ __launch_bounds__(256) void scan_boff_kernel(int* __restrict__ bsum, int nb) {
    int tid = threadIdx.x, lane = tid & 63, wid = tid >> 6;
    int v = (tid < nb) ? bsum[tid] : 0;
    int s = v;
    #pragma unroll
    for (int off = 1; off < 64; off <<= 1) {
        int t = __shfl_up(s, off, 64);
        if (lane >= off) s += t;
    }
    __shared__ int wsum[4];
    if (lane == 63) wsum[wid] = s;
    __syncthreads();
    int wadd = 0;
    #pragma unroll
    for (int w = 0; w < 4; w++) if (w < wid) wadd += wsum[w];
    if (tid < nb) bsum[tid] = wadd + s - v;   // exclusive
}

// exclusive scan with per-block offsets; writes sentinel out[n]
__global__ __launch_bounds__(256) void scan_excl_kernel(const int* __restrict__ in,
                                                        const int* __restrict__ boff,
                                                        int* __restrict__ out, int n) {
    int tid = threadIdx.x, lane = tid & 63, wid = tid >> 6;
    int i = blockIdx.x * 256 + tid;
    int v = (i < n) ? in[i] : 0;
    int s = v;
    #pragma unroll
    for (int off = 1; off < 64; off <<= 1) {
        int t = __shfl_up(s, off, 64);
        if (lane >= off) s += t;
    }
    __shared__ int wsum[4];
    if (lane == 63) wsum[wid] = s;
    __syncthreads();
    int wadd = boff[blockIdx.x];
    #pragma unroll
    for (int w = 0; w < 4; w++) if (w < wid) wadd += wsum[w];
    if (i < n) {
        out[i] = wadd + s - v;
        if (i == n - 1) out[n] = wadd + s;
    }
}

// fallback-path final scan (rowptr + dinv from int counts)
__global__ __launch_bounds__(256) void scan_final_kernel(const int* __restrict__ cnt,
                                                         const int* __restrict__ boff,
                                                         int* __restrict__ rowptr,
                                                         float* __restrict__ dinv, int n) {
    int tid = threadIdx.x, lane = tid & 63, wid = tid >> 6;
    int i = blockIdx.x * 256 + tid;
    int v = (i < n) ? cnt[i] : 0;
    int s = v;
    #pragma unroll
    for (int off = 1; off < 64; off <<= 1) {
        int t = __shfl_up(s, off, 64);
        if (lane >= off) s += t;
    }
    __shared__ int wsum[4];
    if (lane == 63) wsum[wid] = s;
    __syncthreads();
    int wadd = boff[blockIdx.x];
    #pragma unroll
    for (int w = 0; w < 4; w++) if (w < wid) wadd += wsum[w];
    if (i < n) {
        rowptr[i] = wadd + s - v;
        dinv[i]   = rsqrtf((float)v + 1.0f);
        if (i == n - 1) rowptr[n] = wadd + s;
    }
}

// ================= scatters =================
// fallback: packed {src, dinv[src]} in dst-CSR order
__global__ void scatter_kernel(const int* __restrict__ src, const int* __restrict__ dst,
                               const int* __restrict__ rowptr, int* __restrict__ cursor,
                               const float* __restrict__ dinv, int2* __restrict__ epack, int E) {
    int e = blockIdx.x * blockDim.x + threadIdx.x;
    if (e >= E) return;
    int d = dst[e];
    int s = src[e];
    int p = rowptr[d] + atomicAdd(&cursor[d], 1);
    epack[p] = make_int2(s, __float_as_int(dinv[s]));
}

// sliced: bucket by (slice(src), dst)
__global__ void scatter2_kernel(const int* __restrict__ src, const int* __restrict__ dst,
                                const int* __restrict__ rowptr2, int* __restrict__ cursor2,
                                const float* __restrict__ dinv, int2* __restrict__ epack2, int E) {
    int e = blockIdx.x * blockDim.x + threadIdx.x;
    if (e >= E) return;
    int s = src[e], d = dst[e];
    int key = (s / SLICE_N) * NN + d;
    int p = rowptr2[key] + atomicAdd(&cursor2[key], 1);
    epack2[p] = make_int2(s, __float_as_int(dinv[s]));
}

// ================= phase A: slice-pure partial aggregation =================
// block b -> slice s = b%8 (XCD round-robin heuristic), dst chunk = b/8.
// 4 waves x 4 dsts per block; wave = 1 dst row at a time, all 64 lanes on the row.
// F32: gather from fp32 source (C=128, float2/lane); else bf16 (C=256, uint2/lane).
template <int C, bool F32>
__global__ __launch_bounds__(256) void phaseA_kernel(
    const void* __restrict__ h_v, const int* __restrict__ rowptr2,
    const int2* __restrict__ epack2, ushort_t* __restrict__ P, int n) {
    constexpr int V = C / 64;   // bf16 per lane in partial row
    int s = blockIdx.x & 7;
    int chunk = blockIdx.x >> 3;
    int wave = threadIdx.x >> 6, lane = threadIdx.x & 63;
    int d0 = chunk * 16 + wave * 4;
    const int* rp = rowptr2 + (size_t)s * NN;

    #pragma unroll
    for (int di = 0; di < 4; di++) {
        int d = d0 + di;
        if (d >= n) break;
        int eb = rp[d], ee = rp[d + 1];
        float acc[V] = {};
        for (int e = eb; e < ee; e += 2) {
            int2 p0 = epack2[e];
            int2 p1 = epack2[min(e + 1, NE - 1)];
            bool a1 = (e + 1) < ee;                 // wave-uniform
            float w0 = __int_as_float(p0.y);
            float w1 = a1 ? __int_as_float(p1.y) : 0.0f;
            int s0 = p0.x, s1 = a1 ? p1.x : p0.x;
            if constexpr (F32) {
                float2 r0 = *(const float2*)((const float*)h_v + (size_t)s0 * C + lane * 2);
                float2 r1 = *(const float2*)((const float*)h_v + (size_t)s1 * C + lane * 2);
                acc[0] += w0 * r0.x + w1 * r1.x;
                acc[1] += w0 * r0.y + w1 * r1.y;
            } else {
                uint2 r0 = *(const uint2*)((const ushort_t*)h_v + (size_t)s0 * C + lane * 4);
                uint2 r1 = *(const uint2*)((const ushort_t*)h_v + (size_t)s1 * C + lane * 4);
                acc[0] += w0 * __uint_as_float(r0.x << 16) + w1 * __uint_as_float(r1.x << 16);
                acc[1] += w0 * __uint_as_float(r0.x & 0xffff0000u) + w1 * __uint_as_float(r1.x & 0xffff0000u);
                acc[2] += w0 * __uint_as_float(r0.y << 16) + w1 * __uint_as_float(r1.y << 16);
                acc[3] += w0 * __uint_as_float(r0.y & 0xffff0000u) + w1 * __uint_as_float(r1.y & 0xffff0000u);
            }
        }
        ushort_t* o = P + ((size_t)s * NN + d) * C + lane * V;
        if constexpr (V == 4) {
            uint2 ov;
            ov.x = (uint_t)f2bf(acc[0]) | ((uint_t)f2bf(acc[1]) << 16);
            ov.y = (uint_t)f2bf(acc[2]) | ((uint_t)f2bf(acc[3]) << 16);
            *(uint2*)o = ov;
        } else {
            uint_t ov = (uint_t)f2bf(acc[0]) | ((uint_t)f2bf(acc[1]) << 16);
            *(uint_t*)o = ov;
        }
    }
}

// ================= phase B: 8-way partial reduction + epilogue =================
// MODE 0: v = dd*sum + dd^2*self(fp32 x)           -> store bf16
// MODE 1: v = relu(dd*sum + dd^2*self(bf16) + b)   -> store bf16
// MODE 2: like 1, atomicAdd into fp32 out[batch[d]]
template <int C, int MODE>
__global__ __launch_bounds__(256) void phaseB_kernel(
    const ushort_t* __restrict__ P, const void* __restrict__ self_v,
    const float* __restrict__ dinv, const float* __restrict__ bias,
    const int* __restrict__ batch, void* __restrict__ out_v, int n) {
    constexpr int C4 = C / 4;
    int i = blockIdx.x * 256 + threadIdx.x;
    if (i >= n * C4) return;
    int d  = i / C4;
    int c4 = i % C4;

    float sum[4] = {};
    const ushort_t* p = P + (size_t)d * C + c4 * 4;
    #pragma unroll
    for (int sl = 0; sl < NSLICE; sl++) {
        uint2 v = *(const uint2*)(p + (size_t)sl * NN * C);
        sum[0] += __uint_as_float(v.x << 16);
        sum[1] += __uint_as_float(v.x & 0xffff0000u);
        sum[2] += __uint_as_float(v.y << 16);
        sum[3] += __uint_as_float(v.y & 0xffff0000u);
    }

    float dd = dinv[d];
    float self[4];
    if constexpr (MODE == 0) {
        float4 sv = *(const float4*)((const float*)self_v + (size_t)d * C + c4 * 4);
        self[0] = sv.x; self[1] = sv.y; self[2] = sv.z; self[3] = sv.w;
    } else {
        uint2 sv = *(const uint2*)((const ushort_t*)self_v + (size_t)d * C + c4 * 4);
        self[0] = __uint_as_float(sv.x << 16);
        self[1] = __uint_as_float(sv.x & 0xffff0000u);
        self[2] = __uint_as_float(sv.y << 16);
        self[3] = __uint_as_float(sv.y & 0xffff0000u);
    }

    float r[4];
    if constexpr (MODE >= 1) {
        float4 bb = *(const float4*)(bias + c4 * 4);
        float b4[4] = {bb.x, bb.y, bb.z, bb.w};
        #pragma unroll
        for (int k = 0; k < 4; k++)
            r[k] = fmaxf(dd * sum[k] + dd * dd * self[k] + b4[k], 0.0f);
    } else {
        #pragma unroll
        for (int k = 0; k < 4; k++)
            r[k] = dd * sum[k] + dd * dd * self[k];
    }

    if constexpr (MODE == 2) {
        float* o = (float*)out_v + (size_t)batch[d] * C + c4 * 4;
        #pragma unroll
        for (int k = 0; k < 4; k++) atomicAdd(o + k, r[k]);
    } else {
        uint2 ov;
        ov.x = (uint_t)f2bf(r[0]) | ((uint_t)f2bf(r[1]) << 16);
        ov.y = (uint_t)f2bf(r[2]) | ((uint_t)f2bf(r[3]) << 16);
        *(uint2*)((ushort_t*)out_v + (size_t)d * C + c4 * 4) = ov;
    }
}

// ================= fallback: R5 per-node gather aggregation =================
template <int C, int MODE>
__global__ __launch_bounds__(256) void node_agg_kernel(
    const ushort_t* __restrict__ h, const int* __restrict__ rowptr,
    const int2* __restrict__ epack, const float* __restrict__ dinv,
    const float* __restrict__ bias, const int* __restrict__ batch,
    void* __restrict__ out_v, int n) {
    constexpr int V = C / 64;
    int wave = threadIdx.x >> 6;
    int lane = threadIdx.x & 63;
    int d = blockIdx.x * 4 + wave;
    if (d >= n) return;

    int beg = rowptr[d], end = rowptr[d + 1];
    float acc[V] = {};
    for (int e = beg; e < end; e += 8) {
        int   srcs[8];
        float wts[8];
        #pragma unroll
        for (int u = 0; u < 8; u++) {
            int idx = e + u;
            int2 ep = epack[min(idx, NE - 1)];
            bool a = idx < end;
            srcs[u] = a ? ep.x : d;
            wts[u]  = a ? __int_as_float(ep.y) : 0.0f;
        }
        if constexpr (V == 4) {
            uint2 rv[8];
            #pragma unroll
            for (int u = 0; u < 8; u++)
                rv[u] = *(const uint2*)(h + (size_t)srcs[u] * C + lane * 4);
            #pragma unroll
            for (int u = 0; u < 8; u++) {
                float w = wts[u];
                acc[0] += w * __uint_as_float(rv[u].x << 16);
                acc[1] += w * __uint_as_float(rv[u].x & 0xffff0000u);
                acc[2] += w * __uint_as_float(rv[u].y << 16);
                acc[3] += w * __uint_as_float(rv[u].y & 0xffff0000u);
            }
        } else {
            uint_t rv[8];
            #pragma unroll
            for (int u = 0; u < 8; u++)
                rv[u] = *(const uint_t*)(h + (size_t)srcs[u] * C + lane * 2);
            #pragma unroll
            for (int u = 0; u < 8; u++) {
                float w = wts[u];
                acc[0] += w * __uint_as_float(rv[u] << 16);
                acc[1] += w * __uint_as_float(rv[u] & 0xffff0000u);
            }
        }
    }

    float dd = dinv[d];
    float self[V];
    if constexpr (V == 4) {
        uint2 sv = *(const uint2*)(h + (size_t)d * C + lane * 4);
        self[0] = __uint_as_float(sv.x << 16);
        self[1] = __uint_as_float(sv.x & 0xffff0000u);
        self[2] = __uint_as_float(sv.y << 16);
        self[3] = __uint_as_float(sv.y & 0xffff0000u);
    } else {
        uint_t sv = *(const uint_t*)(h + (size_t)d * C + lane * 2);
        self[0] = __uint_as_float(sv << 16);
        self[1] = __uint_as_float(sv & 0xffff0000u);
    }

    float r[V];
    #pragma unroll
    for (int i = 0; i < V; i++) {
        float v = dd * acc[i] + dd * dd * self[i];
        if constexpr (MODE >= 1) v = fmaxf(v + bias[lane * V + i], 0.0f);
        r[i] = v;
    }

    if constexpr (MODE == 2) {
        float* o = (float*)out_v + (size_t)batch[d] * C + lane * V;
        #pragma unroll
        for (int i = 0; i < V; i++) atomicAdd(o + i, r[i]);
    } else if constexpr (V == 4) {
        uint2 o;
        o.x = (uint_t)f2bf(r[0]) | ((uint_t)f2bf(r[1]) << 16);
        o.y = (uint_t)f2bf(r[2]) | ((uint_t)f2bf(r[3]) << 16);
        *(uint2*)((ushort_t*)out_v + (size_t)d * C + lane * 4) = o;
    } else {
        uint_t o = (uint_t)f2bf(r[0]) | ((uint_t)f2bf(r[1]) << 16);
        *(uint_t*)((ushort_t*)out_v + (size_t)d * C + lane * 2) = o;
    }
}

// ================= bf16 MFMA GEMM: C[M,256] = A[M,K] @ Wt[N,K]^T =================
typedef __attribute__((ext_vector_type(8))) short bf16x8;
typedef __attribute__((ext_vector_type(4))) float f32x4;

template <int MODE>
__global__ __launch_bounds__(256) void gemm_bf16_kernel(
    const ushort_t* __restrict__ A, const ushort_t* __restrict__ Wt,
    const float* __restrict__ bias, ushort_t* __restrict__ C, int M, int K) {
    __shared__ ushort_t As[128][40];
    __shared__ ushort_t Bs[128][40];
    int tid = threadIdx.x;
    int row0 = blockIdx.x * 128, col0 = blockIdx.y * 128;
    int lr = tid >> 2, lq = tid & 3;
    int lane = tid & 63, wv = tid >> 6;
    int wr = (wv >> 1) * 64, wc = (wv & 1) * 64;
    int r16 = lane & 15, quad = lane >> 4;

    f32x4 acc[4][4] = {};

    for (int k0 = 0; k0 < K; k0 += 32) {
        {
            int gr0 = row0 + lr, gr1 = row0 + lr + 64;
            uint4 a0 = make_uint4(0, 0, 0, 0), a1 = make_uint4(0, 0, 0, 0);
            if (gr0 < M) a0 = *(const uint4*)(A + (size_t)gr0 * K + k0 + lq * 8);
            if (gr1 < M) a1 = *(const uint4*)(A + (size_t)gr1 * K + k0 + lq * 8);
            *(uint4*)&As[lr][lq * 8]      = a0;
            *(uint4*)&As[lr + 64][lq * 8] = a1;
            uint4 b0 = *(const uint4*)(Wt + (size_t)(col0 + lr) * K + k0 + lq * 8);
            uint4 b1 = *(const uint4*)(Wt + (size_t)(col0 + lr + 64) * K + k0 + lq * 8);
            *(uint4*)&Bs[lr][lq * 8]      = b0;
            *(uint4*)&Bs[lr + 64][lq * 8] = b1;
        }
        __syncthreads();
        bf16x8 af[4], bfr[4];
        #pragma unroll
        for (int i = 0; i < 4; i++) af[i]  = *(const bf16x8*)&As[wr + i * 16 + r16][quad * 8];
        #pragma unroll
        for (int j = 0; j < 4; j++) bfr[j] = *(const bf16x8*)&Bs[wc + j * 16 + r16][quad * 8];
        #pragma unroll
        for (int i = 0; i < 4; i++)
            #pragma unroll
            for (int j = 0; j < 4; j++)
                acc[i][j] = __builtin_amdgcn_mfma_f32_16x16x32_bf16(af[i], bfr[j], acc[i][j], 0, 0, 0);
        __syncthreads();
    }

    #pragma unroll
    for (int j = 0; j < 4; j++) {
        int colc = col0 + wc + j * 16 + r16;
        float bval = (MODE == 1) ? bias[colc] : 0.0f;
        #pragma unroll
        for (int i = 0; i < 4; i++) {
            #pragma unroll
            for (int r = 0; r < 4; r++) {
                int row = row0 + wr + i * 16 + quad * 4 + r;
                if (row < M) {
                    float v = acc[i][j][r];
                    if (MODE == 1) v = fmaxf(v + bval, 0.0f);
                    C[(size_t)row * 256 + colc] = f2bf(v);
                }
            }
        }
    }
}

extern "C" void kernel_launch(void* const* d_in, const int* in_sizes, int n_in,
                              void* d_out, int out_size, void* d_ws, size_t ws_size,
                              hipStream_t stream) {
    const float* x   = (const float*)d_in[0];
    const float* W0  = (const float*)d_in[1];
    const float* b0  = (const float*)d_in[2];
    const float* W1  = (const float*)d_in[3];
    const float* b1  = (const float*)d_in[4];
    const float* W2  = (const float*)d_in[5];
    const float* b2  = (const float*)d_in[6];
    const int*   ei  = (const int*)d_in[7];
    const int*   src = ei;
    const int*   dst = ei + NE;
    const int*   batch = (const int*)d_in[8];
    float* out = (float*)d_out;
    char* ws = (char*)d_ws;

    const dim3 ggrid((NN + 127) / 128, 2);
    const size_t NEED = 266400000ull;

    if (ws_size >= NEED) {
        // ================= sliced (XCD-pure) path =================
        ushort_t* P      = (ushort_t*)ws;                      // [8][NN][256] bf16 204.8 MB
        ushort_t* Abf    = (ushort_t*)(ws + 204800000ull);     // [NN,256] 25.6 MB
        ushort_t* Bbf    = (ushort_t*)(ws + 230400000ull);     // [NN,256] 25.6 MB
        ushort_t* W0t    = (ushort_t*)(ws + 256000000ull);
        ushort_t* W1t    = (ushort_t*)(ws + 256065536ull);
        ushort_t* W2t    = (ushort_t*)(ws + 256196608ull);
        float*    dinv   = (float*)(ws + 256327680ull);        // [NN]
        int*      deg    = (int*)  (ws + 256527680ull);        // [NN]
        int*      cnt2   = (int*)  (ws + 256727680ull);        // [400000]
        int*      rowptr2= (int*)  (ws + 258327680ull);        // [400001]
        int*      boff1  = (int*)  (ws + 259927688ull);        // [1564]
        int*      bsum2  = (int*)  (ws + 259933952ull);        // [8]
        int2*     epack2 = (int2*) (ws + 259933984ull);        // [NE] 6.4 MB

        const int N0 = NSLICE * NN;                  // 400000
        const int blocks0 = (N0 + 255) / 256;        // 1563
        const int blocks1 = (blocks0 + 255) / 256;   // 7
        const int aBlocks = NSLICE * ((NN + 15) / 16);   // 8 * 3125
        const int b256 = (NN * (CH / 4) + 255) / 256;    // 12500
        const int b128 = (NN * (CIN / 4) + 255) / 256;   // 6250

        conv_wt_kernel<<<(CIN * CH + 255) / 256, 256, 0, stream>>>(W0, W0t, CIN, CH);
        conv_wt_kernel<<<(CH * CH + 255) / 256, 256, 0, stream>>>(W1, W1t, CH, CH);
        conv_wt_kernel<<<(CH * CH + 255) / 256, 256, 0, stream>>>(W2, W2t, CH, CH);

        // counts + dinv + bucket CSR
        hipMemsetAsync(deg, 0, (size_t)NN * 4, stream);
        hipMemsetAsync(cnt2, 0, (size_t)N0 * 4, stream);
        count_both_kernel<<<(NE + 255) / 256, 256, 0, stream>>>(src, dst, deg, cnt2, NE);
        dinv_from_deg_kernel<<<(NN + 255) / 256, 256, 0, stream>>>(deg, dinv, NN);
        scan_bsum_kernel<<<blocks0, 256, 0, stream>>>(cnt2, boff1, N0);
        scan_bsum_kernel<<<blocks1, 256, 0, stream>>>(boff1, bsum2, blocks0);
        scan_boff_kernel<<<1, 256, 0, stream>>>(bsum2, blocks1);
        scan_excl_kernel<<<blocks1, 256, 0, stream>>>(boff1, bsum2, boff1, blocks0);
        scan_excl_kernel<<<blocks0, 256, 0, stream>>>(cnt2, boff1, rowptr2, N0);
        hipMemsetAsync(cnt2, 0, (size_t)N0 * 4, stream);  // cursor
        scatter2_kernel<<<(NE + 255) / 256, 256, 0, stream>>>(src, dst, rowptr2, cnt2, dinv, epack2, NE);

        // layer 0: sliced agg of fp32 x (128 ch) -> Bbf, then GEMM0 (bias+relu)
        phaseA_kernel<CIN, true><<<aBlocks, 256, 0, stream>>>(x, rowptr2, epack2, P, NN);
        phaseB_kernel<CIN, 0><<<b128, 256, 0, stream>>>(P, x, dinv, nullptr, nullptr, Bbf, NN);
        gemm_bf16_kernel<1><<<ggrid, 256, 0, stream>>>(Bbf, W0t, b0, Abf, NN, CIN);

        // layer 1
        gemm_bf16_kernel<0><<<ggrid, 256, 0, stream>>>(Abf, W1t, nullptr, Bbf, NN, CH);
        phaseA_kernel<CH, false><<<aBlocks, 256, 0, stream>>>(Bbf, rowptr2, epack2, P, NN);
        phaseB_kernel<CH, 1><<<b256, 256, 0, stream>>>(P, Bbf, dinv, b1, nullptr, Abf, NN);

        // layer 2 + pool
        gemm_bf16_kernel<0><<<ggrid, 256, 0, stream>>>(Abf, W2t, nullptr, Bbf, NN, CH);
        phaseA_kernel<CH, false><<<aBlocks, 256, 0, stream>>>(Bbf, rowptr2, epack2, P, NN);
        hipMemsetAsync(out, 0, (size_t)NG * CH * 4, stream);
        phaseB_kernel<CH, 2><<<b256, 256, 0, stream>>>(P, Bbf, dinv, b2, batch, out, NN);
    } else {
        // ================= fallback: R5 path =================
        ushort_t* Abf = (ushort_t*)ws;
        ushort_t* Bbf = (ushort_t*)(ws + 25600000ull);
        ushort_t* xbf = (ushort_t*)(ws + 51200000ull);
        ushort_t* W0t = (ushort_t*)(ws + 64000000ull);
        ushort_t* W1t = (ushort_t*)(ws + 64065536ull);
        ushort_t* W2t = (ushort_t*)(ws + 64196608ull);
        float*    dinv   = (float*)(ws + 64327680ull);
        int*      rowptr = (int*)  (ws + 64527680ull);
        int*      cnt    = (int*)  (ws + 64727808ull);
        int2*     epack  = (int2*) (ws + 64927808ull);
        int*      bsum   = (int*)  (ws + 71327808ull);

        const int scanBlocks = (NN + 255) / 256;
        const int nodeBlocks = (NN + 3) / 4;

        conv_x_kernel<<<(NN * CIN / 4 + 255) / 256, 256, 0, stream>>>((const float4*)x, (ushort4*)xbf, NN * CIN / 4);
        conv_wt_kernel<<<(CIN * CH + 255) / 256, 256, 0, stream>>>(W0, W0t, CIN, CH);
        conv_wt_kernel<<<(CH * CH + 255) / 256, 256, 0, stream>>>(W1, W1t, CH, CH);
        conv_wt_kernel<<<(CH * CH + 255) / 256, 256, 0, stream>>>(W2, W2t, CH, CH);

        hipMemsetAsync(cnt, 0, (size_t)NN * 4, stream);
        count_kernel<<<(NE + 255) / 256, 256, 0, stream>>>(dst, cnt, NE);
        scan_bsum_kernel<<<scanBlocks, 256, 0, stream>>>(cnt, bsum, NN);
        scan_boff_kernel<<<1, 256, 0, stream>>>(bsum, scanBlocks);
        scan_final_kernel<<<scanBlocks, 256, 0, stream>>>(cnt, bsum, rowptr, dinv, NN);
        hipMemsetAsync(cnt, 0, (size_t)NN * 4, stream);
        scatter_kernel<<<(NE + 255) / 256, 256, 0, stream>>>(src, dst, rowptr, cnt, dinv, epack, NE);

        node_agg_kernel<CIN, 0><<<nodeBlocks, 256, 0, stream>>>(xbf, rowptr, epack, dinv, nullptr, nullptr, Bbf, NN);
        gemm_bf16_kernel<1><<<ggrid, 256, 0, stream>>>(Bbf, W0t, b0, Abf, NN, CIN);
        gemm_bf16_kernel<0><<<ggrid, 256, 0, stream>>>(Abf, W1t, nullptr, Bbf, NN, CH);
        node_agg_kernel<CH, 1><<<nodeBlocks, 256, 0, stream>>>(Bbf, rowptr, epack, dinv, b1, nullptr, Abf, NN);
        gemm_bf16_kernel<0><<<ggrid, 256, 0, stream>>>(Abf, W2t, nullptr, Bbf, NN, CH);
        hipMemsetAsync(out, 0, (size_t)NG * CH * 4, stream);
        node_agg_kernel<CH, 2><<<nodeBlocks, 256, 0, stream>>>(Bbf, rowptr, epack, dinv, b2, batch, out, NN);
    }
}

// Round 7
// 461.007 us; speedup vs baseline: 1.7914x; 1.7914x over previous
//
#include <hip/hip_runtime.h>

constexpr int NN  = 50000;   // nodes
constexpr int NE  = 800000;  // edges
constexpr int CIN = 128;     // input channels
constexpr int CH  = 256;     // hidden channels
constexpr int NG  = 512;     // graphs

typedef unsigned short ushort_t;
typedef unsigned int uint_t;

static __device__ __forceinline__ ushort_t f2bf(float f) {
    uint_t u = __float_as_uint(f);
    u += 0x7fffu + ((u >> 16) & 1u);   // round-to-nearest-even
    return (ushort_t)(u >> 16);
}

// ================= prep: fp32 -> bf16 converts =================
__global__ void conv_x_kernel(const float4* __restrict__ x, ushort4* __restrict__ xb, int n4) {
    int i = blockIdx.x * blockDim.x + threadIdx.x;
    if (i >= n4) return;
    float4 v = x[i];
    ushort4 o;
    o.x = f2bf(v.x); o.y = f2bf(v.y); o.z = f2bf(v.z); o.w = f2bf(v.w);
    xb[i] = o;
}

// Wt[n*K + k] = bf16(W[k*N + n])
__global__ void conv_wt_kernel(const float* __restrict__ W, ushort_t* __restrict__ Wt, int K, int N) {
    int i = blockIdx.x * blockDim.x + threadIdx.x;
    if (i >= K * N) return;
    int k = i / N, n = i % N;
    Wt[(size_t)n * K + k] = f2bf(W[i]);
}

// ================= CSR build =================
__global__ void count_kernel(const int* __restrict__ dst, int* __restrict__ cnt, int E) {
    int e = blockIdx.x * blockDim.x + threadIdx.x;
    if (e < E) atomicAdd(&cnt[dst[e]], 1);
}

__global__ __launch_bounds__(256) void scan_bsum_kernel(const int* __restrict__ cnt,
                                                        int* __restrict__ bsum, int n) {
    int i = blockIdx.x * 256 + threadIdx.x;
    int v = (i < n) ? cnt[i] : 0;
    #pragma unroll
    for (int off = 32; off >= 1; off >>= 1) v += __shfl_xor(v, off, 64);
    __shared__ int ws[4];
    if ((threadIdx.x & 63) == 0) ws[threadIdx.x >> 6] = v;
    __syncthreads();
    if (threadIdx.x == 0) bsum[blockIdx.x] = ws[0] + ws[1] + ws[2] + ws[3];
}

__global__ __launch_bounds__(256) void scan_boff_kernel(int* __restrict__ bsum, int nb) {
    int tid = threadIdx.x, lane = tid & 63, wid = tid >> 6;
    int v = (tid < nb) ? bsum[tid] : 0;
    int s = v;
    #pragma unroll
    for (int off = 1; off < 64; off <<= 1) {
        int t = __shfl_up(s, off, 64);
        if (lane >= off) s += t;
    }
    __shared__ int wsum[4];
    if (lane == 63) wsum[wid] = s;
    __syncthreads();
    int wadd = 0;
    #pragma unroll
    for (int w = 0; w < 4; w++) if (w < wid) wadd += wsum[w];
    if (tid < nb) bsum[tid] = wadd + s - v;   // exclusive
}

__global__ __launch_bounds__(256) void scan_final_kernel(const int* __restrict__ cnt,
                                                         const int* __restrict__ boff,
                                                         int* __restrict__ rowptr,
                                                         float* __restrict__ dinv, int n) {
    int tid = threadIdx.x, lane = tid & 63, wid = tid >> 6;
    int i = blockIdx.x * 256 + tid;
    int v = (i < n) ? cnt[i] : 0;
    int s = v;
    #pragma unroll
    for (int off = 1; off < 64; off <<= 1) {
        int t = __shfl_up(s, off, 64);
        if (lane >= off) s += t;
    }
    __shared__ int wsum[4];
    if (lane == 63) wsum[wid] = s;
    __syncthreads();
    int wadd = boff[blockIdx.x];
    #pragma unroll
    for (int w = 0; w < 4; w++) if (w < wid) wadd += wsum[w];
    if (i < n) {
        rowptr[i] = wadd + s - v;
        dinv[i]   = rsqrtf((float)v + 1.0f);   // +1 self loop
        if (i == n - 1) rowptr[n] = wadd + s;
    }
}

// scatter: write packed {src, dinv[src]} per CSR slot
__global__ void scatter_kernel(const int* __restrict__ src, const int* __restrict__ dst,
                               const int* __restrict__ rowptr, int* __restrict__ cursor,
                               const float* __restrict__ dinv, int2* __restrict__ epack, int E) {
    int e = blockIdx.x * blockDim.x + threadIdx.x;
    if (e >= E) return;
    int d = dst[e];
    int s = src[e];
    int p = rowptr[d] + atomicAdd(&cursor[d], 1);
    epack[p] = make_int2(s, __float_as_int(dinv[s]));
}

// ================= per-node gather aggregation (bf16) ====
// One wave per node. 4 B/lane loads ONLY (empirically ~3x faster per instr
// than 8 B/lane): C=256 -> two 256 B half-row loads per row; C=128 -> one.
// Lane l handles channels {2l,2l+1} (+ {128+2l,128+2l+1} for C=256).
// MODE 0: out(bf16) = dd*sum + dd^2*self
// MODE 1: out(bf16) = relu(dd*sum + dd^2*self + bias)
// MODE 2: atomicAdd relu(...) into fp32 out[batch[d]]
template <int C, int MODE>
__global__ __launch_bounds__(256) void node_agg_kernel(
    const ushort_t* __restrict__ h, const int* __restrict__ rowptr,
    const int2* __restrict__ epack, const float* __restrict__ dinv,
    const float* __restrict__ bias, const int* __restrict__ batch,
    void* __restrict__ out_v, int n) {
    constexpr int V = C / 64;                 // bf16 per lane (2 or 4)
    int wave = threadIdx.x >> 6;
    int lane = threadIdx.x & 63;
    int d = blockIdx.x * 4 + wave;
    if (d >= n) return;

    int beg = rowptr[d], end = rowptr[d + 1];
    float acc[V] = {};

    for (int e = beg; e < end; e += 8) {
        int   srcs[8];
        float wts[8];
        #pragma unroll
        for (int u = 0; u < 8; u++) {
            int idx = e + u;
            int2 ep = epack[min(idx, NE - 1)];
            bool a = idx < end;               // wave-uniform
            srcs[u] = a ? ep.x : d;
            wts[u]  = a ? __int_as_float(ep.y) : 0.0f;
        }
        if constexpr (V == 4) {
            uint_t ra[8], rb[8];
            #pragma unroll
            for (int u = 0; u < 8; u++) {
                const uint_t* row = (const uint_t*)(h + (size_t)srcs[u] * C);
                ra[u] = row[lane];            // channels 2l,2l+1 (bytes 0..255)
                rb[u] = row[64 + lane];       // channels 128+2l,128+2l+1
            }
            #pragma unroll
            for (int u = 0; u < 8; u++) {
                float w = wts[u];
                acc[0] += w * __uint_as_float(ra[u] << 16);
                acc[1] += w * __uint_as_float(ra[u] & 0xffff0000u);
                acc[2] += w * __uint_as_float(rb[u] << 16);
                acc[3] += w * __uint_as_float(rb[u] & 0xffff0000u);
            }
        } else {
            uint_t rv[8];
            #pragma unroll
            for (int u = 0; u < 8; u++)
                rv[u] = ((const uint_t*)(h + (size_t)srcs[u] * C))[lane];
            #pragma unroll
            for (int u = 0; u < 8; u++) {
                float w = wts[u];
                acc[0] += w * __uint_as_float(rv[u] << 16);
                acc[1] += w * __uint_as_float(rv[u] & 0xffff0000u);
            }
        }
    }

    float dd = dinv[d];
    float self[V];
    {
        const uint_t* row = (const uint_t*)(h + (size_t)d * C);
        uint_t sa = row[lane];
        self[0] = __uint_as_float(sa << 16);
        self[1] = __uint_as_float(sa & 0xffff0000u);
        if constexpr (V == 4) {
            uint_t sb = row[64 + lane];
            self[2] = __uint_as_float(sb << 16);
            self[3] = __uint_as_float(sb & 0xffff0000u);
        }
    }

    float r[V];
    if constexpr (MODE >= 1) {
        float2 bA = *(const float2*)(bias + 2 * lane);
        r[0] = fmaxf(dd * acc[0] + dd * dd * self[0] + bA.x, 0.0f);
        r[1] = fmaxf(dd * acc[1] + dd * dd * self[1] + bA.y, 0.0f);
        if constexpr (V == 4) {
            float2 bB = *(const float2*)(bias + 128 + 2 * lane);
            r[2] = fmaxf(dd * acc[2] + dd * dd * self[2] + bB.x, 0.0f);
            r[3] = fmaxf(dd * acc[3] + dd * dd * self[3] + bB.y, 0.0f);
        }
    } else {
        #pragma unroll
        for (int i = 0; i < V; i++)
            r[i] = dd * acc[i] + dd * dd * self[i];
    }

    if constexpr (MODE == 2) {
        float* o = (float*)out_v + (size_t)batch[d] * C;
        atomicAdd(o + 2 * lane, r[0]);
        atomicAdd(o + 2 * lane + 1, r[1]);
        if constexpr (V == 4) {
            atomicAdd(o + 128 + 2 * lane, r[2]);
            atomicAdd(o + 128 + 2 * lane + 1, r[3]);
        }
    } else {
        uint_t* o = (uint_t*)((ushort_t*)out_v + (size_t)d * C);
        o[lane] = (uint_t)f2bf(r[0]) | ((uint_t)f2bf(r[1]) << 16);
        if constexpr (V == 4)
            o[64 + lane] = (uint_t)f2bf(r[2]) | ((uint_t)f2bf(r[3]) << 16);
    }
}

// ================= bf16 MFMA GEMM: C[M,256] = A[M,K] @ Wt[N,K]^T =================
typedef __attribute__((ext_vector_type(8))) short bf16x8;
typedef __attribute__((ext_vector_type(4))) float f32x4;

template <int MODE>
__global__ __launch_bounds__(256) void gemm_bf16_kernel(
    const ushort_t* __restrict__ A, const ushort_t* __restrict__ Wt,
    const float* __restrict__ bias, ushort_t* __restrict__ C, int M, int K) {
    __shared__ ushort_t As[128][40];
    __shared__ ushort_t Bs[128][40];
    int tid = threadIdx.x;
    int row0 = blockIdx.x * 128, col0 = blockIdx.y * 128;
    int lr = tid >> 2, lq = tid & 3;
    int lane = tid & 63, wv = tid >> 6;
    int wr = (wv >> 1) * 64, wc = (wv & 1) * 64;
    int r16 = lane & 15, quad = lane >> 4;

    f32x4 acc[4][4] = {};

    for (int k0 = 0; k0 < K; k0 += 32) {
        {
            int gr0 = row0 + lr, gr1 = row0 + lr + 64;
            uint4 a0 = make_uint4(0, 0, 0, 0), a1 = make_uint4(0, 0, 0, 0);
            if (gr0 < M) a0 = *(const uint4*)(A + (size_t)gr0 * K + k0 + lq * 8);
            if (gr1 < M) a1 = *(const uint4*)(A + (size_t)gr1 * K + k0 + lq * 8);
            *(uint4*)&As[lr][lq * 8]      = a0;
            *(uint4*)&As[lr + 64][lq * 8] = a1;
            uint4 b0 = *(const uint4*)(Wt + (size_t)(col0 + lr) * K + k0 + lq * 8);
            uint4 b1 = *(const uint4*)(Wt + (size_t)(col0 + lr + 64) * K + k0 + lq * 8);
            *(uint4*)&Bs[lr][lq * 8]      = b0;
            *(uint4*)&Bs[lr + 64][lq * 8] = b1;
        }
        __syncthreads();
        bf16x8 af[4], bfr[4];
        #pragma unroll
        for (int i = 0; i < 4; i++) af[i]  = *(const bf16x8*)&As[wr + i * 16 + r16][quad * 8];
        #pragma unroll
        for (int j = 0; j < 4; j++) bfr[j] = *(const bf16x8*)&Bs[wc + j * 16 + r16][quad * 8];
        #pragma unroll
        for (int i = 0; i < 4; i++)
            #pragma unroll
            for (int j = 0; j < 4; j++)
                acc[i][j] = __builtin_amdgcn_mfma_f32_16x16x32_bf16(af[i], bfr[j], acc[i][j], 0, 0, 0);
        __syncthreads();
    }

    #pragma unroll
    for (int j = 0; j < 4; j++) {
        int colc = col0 + wc + j * 16 + r16;
        float bval = (MODE == 1) ? bias[colc] : 0.0f;
        #pragma unroll
        for (int i = 0; i < 4; i++) {
            #pragma unroll
            for (int r = 0; r < 4; r++) {
                int row = row0 + wr + i * 16 + quad * 4 + r;
                if (row < M) {
                    float v = acc[i][j][r];
                    if (MODE == 1) v = fmaxf(v + bval, 0.0f);
                    C[(size_t)row * 256 + colc] = f2bf(v);
                }
            }
        }
    }
}

extern "C" void kernel_launch(void* const* d_in, const int* in_sizes, int n_in,
                              void* d_out, int out_size, void* d_ws, size_t ws_size,
                              hipStream_t stream) {
    const float* x   = (const float*)d_in[0];
    const float* W0  = (const float*)d_in[1];
    const float* b0  = (const float*)d_in[2];
    const float* W1  = (const float*)d_in[3];
    const float* b1  = (const float*)d_in[4];
    const float* W2  = (const float*)d_in[5];
    const float* b2  = (const float*)d_in[6];
    const int*   ei  = (const int*)d_in[7];
    const int*   src = ei;
    const int*   dst = ei + NE;
    const int*   batch = (const int*)d_in[8];
    float* out = (float*)d_out;

    char* ws = (char*)d_ws;
    ushort_t* Abf = (ushort_t*)ws;                        // [NN,256] bf16  25.6 MB
    ushort_t* Bbf = (ushort_t*)(ws + 25600000ull);        // [NN,256] bf16  25.6 MB
    ushort_t* xbf = (ushort_t*)(ws + 51200000ull);        // [NN,128] bf16  12.8 MB
    ushort_t* W0t = (ushort_t*)(ws + 64000000ull);        // [256,128] bf16
    ushort_t* W1t = (ushort_t*)(ws + 64065536ull);        // [256,256] bf16
    ushort_t* W2t = (ushort_t*)(ws + 64196608ull);        // [256,256] bf16
    float*    dinv   = (float*)(ws + 64327680ull);        // [NN]
    int*      rowptr = (int*)  (ws + 64527680ull);        // [NN+1]
    int*      cnt    = (int*)  (ws + 64727808ull);        // [NN]
    int2*     epack  = (int2*) (ws + 64927808ull);        // [NE] {src, dinv[src]} 6.4 MB
    int*      bsum   = (int*)  (ws + 71327808ull);        // [<=256]

    const int scanBlocks = (NN + 255) / 256;              // 196
    const int nodeBlocks = (NN + 3) / 4;                  // 1 node per wave, 4 waves/block
    const dim3 ggrid((NN + 127) / 128, 2);

    // --- prep converts ---
    conv_x_kernel<<<(NN * CIN / 4 + 255) / 256, 256, 0, stream>>>((const float4*)x, (ushort4*)xbf, NN * CIN / 4);
    conv_wt_kernel<<<(CIN * CH + 255) / 256, 256, 0, stream>>>(W0, W0t, CIN, CH);
    conv_wt_kernel<<<(CH * CH + 255) / 256, 256, 0, stream>>>(W1, W1t, CH, CH);
    conv_wt_kernel<<<(CH * CH + 255) / 256, 256, 0, stream>>>(W2, W2t, CH, CH);

    // --- CSR + normalization ---
    hipMemsetAsync(cnt, 0, (size_t)NN * 4, stream);
    count_kernel<<<(NE + 255) / 256, 256, 0, stream>>>(dst, cnt, NE);
    scan_bsum_kernel<<<scanBlocks, 256, 0, stream>>>(cnt, bsum, NN);
    scan_boff_kernel<<<1, 256, 0, stream>>>(bsum, scanBlocks);
    scan_final_kernel<<<scanBlocks, 256, 0, stream>>>(cnt, bsum, rowptr, dinv, NN);
    hipMemsetAsync(cnt, 0, (size_t)NN * 4, stream);       // reuse as cursor
    scatter_kernel<<<(NE + 255) / 256, 256, 0, stream>>>(src, dst, rowptr, cnt, dinv, epack, NE);

    // --- layer 0: aggregate x (128 ch), GEMM0 fused bias+relu ---
    node_agg_kernel<CIN, 0><<<nodeBlocks, 256, 0, stream>>>(xbf, rowptr, epack, dinv, nullptr, nullptr, Bbf, NN);
    gemm_bf16_kernel<1><<<ggrid, 256, 0, stream>>>(Bbf, W0t, b0, Abf, NN, CIN);

    // --- layer 1: GEMM1 plain, aggregate fused bias+relu ---
    gemm_bf16_kernel<0><<<ggrid, 256, 0, stream>>>(Abf, W1t, nullptr, Bbf, NN, CH);
    node_agg_kernel<CH, 1><<<nodeBlocks, 256, 0, stream>>>(Bbf, rowptr, epack, dinv, b1, nullptr, Abf, NN);

    // --- layer 2: GEMM2 plain, aggregate fused bias+relu+pool ---
    gemm_bf16_kernel<0><<<ggrid, 256, 0, stream>>>(Abf, W2t, nullptr, Bbf, NN, CH);
    hipMemsetAsync(out, 0, (size_t)NG * CH * 4, stream);
    node_agg_kernel<CH, 2><<<nodeBlocks, 256, 0, stream>>>(Bbf, rowptr, epack, dinv, b2, batch, out, NN);
}